// Round 5
// baseline (537.691 us; speedup 1.0000x reference)
//
#include <hip/hip_runtime.h>
#include <hip/hip_fp16.h>
#include <cstddef>
#include <cstdint>

#define B 256
#define N 2048
#define DH 128
#define DG 256
#define HID 256
#define WAVES 16
#define TPB (WAVES * 64)     // 1024 threads, 16 waves, 1 block/CU = 4 waves/SIMD
#define RPI (WAVES * 8)      // 128 rows per block-iteration
#define KIT (N / RPI)        // 16 k-iterations per pass
#define SCALE 0.08838834764831845f
#define LN_EPS 1e-5f
#define TAN_NORM_MAX 6.2f    // artanh(1-1e-5)=6.103; safe upper bound

// ---------- helpers ----------

__device__ __forceinline__ float artanh_clip(float a) {
  a = fminf(a, 1.0f - 1e-5f);
  return 0.5f * __logf((1.0f + a) / (1.0f - a));
}

__device__ __forceinline__ float logmap_scale(float n2) {
  float nc = fmaxf(sqrtf(n2), 1e-7f);
  return artanh_clip(nc) / nc;
}

// allreduce-sum across each 16-lane DPP row using ROW_ROR (pure VALU)
__device__ __forceinline__ float row16_sum(float x) {
  x += __int_as_float(__builtin_amdgcn_update_dpp(0, __float_as_int(x), 0x128, 0xF, 0xF, true)); // ror:8
  x += __int_as_float(__builtin_amdgcn_update_dpp(0, __float_as_int(x), 0x124, 0xF, 0xF, true)); // ror:4
  x += __int_as_float(__builtin_amdgcn_update_dpp(0, __float_as_int(x), 0x122, 0xF, 0xF, true)); // ror:2
  x += __int_as_float(__builtin_amdgcn_update_dpp(0, __float_as_int(x), 0x121, 0xF, 0xF, true)); // ror:1
  return x;
}

__device__ __forceinline__ float wave_allsum(float v) {
#pragma unroll
  for (int m = 1; m < 64; m <<= 1) v += __shfl_xor(v, m);
  return v;
}

__device__ __forceinline__ float dot128(const float* __restrict__ wrow,
                                        const float* __restrict__ x) {
  const float4* a = (const float4*)wrow;
  const float4* v = (const float4*)x;
  float s = 0.f;
#pragma unroll
  for (int j = 0; j < 32; ++j) {
    float4 u = a[j], b = v[j];
    s += u.x * b.x + u.y * b.y + u.z * b.z + u.w * b.w;
  }
  return s;
}

__device__ __forceinline__ float dot256(const float* __restrict__ wrow,
                                        const float* __restrict__ x) {
  const float4* a = (const float4*)wrow;
  const float4* v = (const float4*)x;
  float s = 0.f;
#pragma unroll
  for (int j = 0; j < 64; ++j) {
    float4 u = a[j], b = v[j];
    s += u.x * b.x + u.y * b.y + u.z * b.z + u.w * b.w;
  }
  return s;
}

// ---------- fused per-batch refiner: one block = one batch, all passes ----------
// Pass 0 reads fp32 demo (cold HBM), computes tangent rows y = ts*row, stores y
// as fp16 to a workspace cache. Passes 1-2 read the fp16 cache (128 MB,
// L3-resident): half the bytes, no logmap chain.
// 16 waves/block (4 waves/SIMD): the R0-R3 counters showed 2 waves/SIMD left
// everything (HBM 20%, VALU 15-30%, Occ 23%) unsaturated -> per-wave
// serialization was the bottleneck; double TLP to hide it.
// k-loop is the simple 1-deep prefetch (depth-4 rotation only caused spill).

__global__ __launch_bounds__(TPB, 4) void fused_refiner(
    const float* __restrict__ demo, const float* __restrict__ rho,
    const float* __restrict__ seed_g_w, const float* __restrict__ seed_g_b,
    const float* __restrict__ seed_d_w, const float* __restrict__ pool_wq_w,
    const float* __restrict__ pool_wk_w, const float* __restrict__ pool_wv_w,
    const float* __restrict__ q_u_w, const float* __restrict__ q_g_w,
    const float* __restrict__ q_g_b, const float* __restrict__ kv_w,
    const float* __restrict__ mlp_w1, const float* __restrict__ mlp_b1,
    const float* __restrict__ mlp_w2, const float* __restrict__ mlp_b2,
    const float* __restrict__ ln_g, const float* __restrict__ ln_b,
    __half* __restrict__ ycache, float* __restrict__ out) {
  const int b = blockIdx.x;
  const int tid = threadIdx.x;
  const int w = tid >> 6;
  const int lane = tid & 63;
  const int g = lane >> 4;   // row within wave's 4-row group
  const int il = lane & 15;  // 16 lanes per row

  __shared__ __align__(16) float s_rho[DG];
  __shared__ __align__(16) float s_x[DH];
  __shared__ __align__(16) float s_y[DH];
  __shared__ __align__(16) float s_h[HID];
  __shared__ __align__(16) float s_ut[DH];
  __shared__ __align__(16) float s_qseed[DH];
  __shared__ __align__(16) float s_qvec[DH];
  __shared__ __align__(16) float s_fold[WAVES][DH];
  __shared__ float s_l[WAVES];
  __shared__ float s_red[WAVES];
  __shared__ float s_Mb;

  // block-wide sum; all threads must call (inactive contribute 0)
  auto bsumAll = [&](float v) -> float {
    v = wave_allsum(v);
    if (lane == 0) s_red[w] = v;
    __syncthreads();
    float r = 0.f;
#pragma unroll
    for (int j = 0; j < WAVES; ++j) r += s_red[j];
    __syncthreads();
    return r;
  };

  // shared epilogue: expmap -> logmap -> LN -> q -> qvec -> Mb
  auto ln_query = [&](float v) {
    float n2 = bsumAll(tid < DH ? v * v : 0.f);
    float u = 0.f, ut = 0.f;
    if (tid < DH) {
      float nc = fmaxf(sqrtf(n2), 1e-7f);
      u = v * (tanhf(nc) / nc);
    }
    float nu2 = bsumAll(tid < DH ? u * u : 0.f);
    if (tid < DH) {
      float nuc = fmaxf(sqrtf(nu2), 1e-7f);
      ut = u * (artanh_clip(nuc) / nuc);
    }
    float mu = bsumAll(tid < DH ? ut : 0.f) * (1.0f / DH);
    float d = ut - mu;
    float var = bsumAll(tid < DH ? d * d : 0.f) * (1.0f / DH);
    if (tid < DH) {
      float y = d * rsqrtf(var + LN_EPS) * ln_g[tid] + ln_b[tid];
      s_ut[tid] = y;
      s_x[tid] = y;
    }
    __syncthreads();
    if (tid < DH) {
      s_y[tid] = q_g_b[tid] + dot128(q_u_w + (size_t)tid * DH, s_x) +
                 dot256(q_g_w + (size_t)tid * DG, s_rho);
    }
    __syncthreads();
    float qp = 0.f;
    if (tid < DH) {
#pragma unroll 8
      for (int i = 0; i < DH; ++i) qp += kv_w[i * DH + tid] * s_y[i];
      s_qvec[tid] = qp;
    }
    float qn2 = bsumAll(tid < DH ? qp * qp : 0.f);
    if (tid == 0) s_Mb = SCALE * TAN_NORM_MAX * sqrtf(qn2);
    __syncthreads();
  };

  // ---- setup: q_seed, pooled-attention query, Mb ----
  if (tid < DG) s_rho[tid] = rho[(size_t)b * DG + tid];
  __syncthreads();
  if (tid < DH) {
    float qs = seed_g_b[tid] + dot256(seed_g_w + (size_t)tid * DG, s_rho);
    s_qseed[tid] = qs;
    s_x[tid] = qs;
  }
  __syncthreads();
  if (tid < DH) s_y[tid] = dot128(pool_wq_w + (size_t)tid * DH, s_x);
  __syncthreads();
  float qp0 = 0.f;
  if (tid < DH) {
#pragma unroll 8
    for (int i = 0; i < DH; ++i) qp0 += pool_wk_w[i * DH + tid] * s_y[i];
    s_qvec[tid] = qp0;
  }
  float qn2 = bsumAll(tid < DH ? qp0 * qp0 : 0.f);
  if (tid == 0) s_Mb = SCALE * TAN_NORM_MAX * sqrtf(qn2);
  __syncthreads();

  const float* demo_b = demo + (size_t)b * N * DH;
  __half* yc_b = ycache + (size_t)b * N * DH;

  for (int pass = 0; pass < 3; ++pass) {
    const float4 qv0 = *(const float4*)&s_qvec[il * 4];
    const float4 qv1 = *(const float4*)&s_qvec[64 + il * 4];
    const float Mb = s_Mb;

    float lsum = 0.f;
    float4 accL = make_float4(0.f, 0.f, 0.f, 0.f);
    float4 accH = make_float4(0.f, 0.f, 0.f, 0.f);

    if (pass == 0) {
      // ---- fp32 source pass: compute ts, emit fp16 y-cache ----
      const float* p = demo_b + (size_t)(w * 8 + g) * DH + il * 4;
      __half* yw = yc_b + (size_t)(w * 8 + g) * DH + (size_t)il * 8;

      float4 xa1 = *(const float4*)(p);
      float4 xa2 = *(const float4*)(p + 64);
      float4 xb1 = *(const float4*)(p + 4 * DH);
      float4 xb2 = *(const float4*)(p + 4 * DH + 64);

      for (int k = 0; k < KIT; ++k) {
        float4 ca1 = xa1, ca2 = xa2, cb1 = xb1, cb2 = xb2;
        if (k + 1 < KIT) {
          const float* pn = p + (size_t)(k + 1) * RPI * DH;
          xa1 = *(const float4*)(pn);
          xa2 = *(const float4*)(pn + 64);
          xb1 = *(const float4*)(pn + 4 * DH);
          xb2 = *(const float4*)(pn + 4 * DH + 64);
        }
        // group A (row k*RPI + w*8 + g)
        {
          float dd = qv0.x * ca1.x + qv0.y * ca1.y + qv0.z * ca1.z + qv0.w * ca1.w +
                     qv1.x * ca2.x + qv1.y * ca2.y + qv1.z * ca2.z + qv1.w * ca2.w;
          float n2 = ca1.x * ca1.x + ca1.y * ca1.y + ca1.z * ca1.z + ca1.w * ca1.w +
                     ca2.x * ca2.x + ca2.y * ca2.y + ca2.z * ca2.z + ca2.w * ca2.w;
          dd = row16_sum(dd);
          n2 = row16_sum(n2);
          float tsv = logmap_scale(n2);
          float4 y1 = make_float4(tsv * ca1.x, tsv * ca1.y, tsv * ca1.z, tsv * ca1.w);
          float4 y2 = make_float4(tsv * ca2.x, tsv * ca2.y, tsv * ca2.z, tsv * ca2.w);
          __half2 h01 = __float22half2_rn(make_float2(y1.x, y1.y));
          __half2 h23 = __float22half2_rn(make_float2(y1.z, y1.w));
          __half2 h45 = __float22half2_rn(make_float2(y2.x, y2.y));
          __half2 h67 = __float22half2_rn(make_float2(y2.z, y2.w));
          uint4 pk;
          pk.x = *(const unsigned*)&h01; pk.y = *(const unsigned*)&h23;
          pk.z = *(const unsigned*)&h45; pk.w = *(const unsigned*)&h67;
          *(uint4*)(yw + (size_t)k * RPI * DH) = pk;
          float pw = __expf(dd * tsv * SCALE - Mb);
          lsum += pw;
          accL.x += pw * y1.x; accL.y += pw * y1.y; accL.z += pw * y1.z; accL.w += pw * y1.w;
          accH.x += pw * y2.x; accH.y += pw * y2.y; accH.z += pw * y2.z; accH.w += pw * y2.w;
        }
        // group B (row k*RPI + w*8 + 4 + g)
        {
          float dd = qv0.x * cb1.x + qv0.y * cb1.y + qv0.z * cb1.z + qv0.w * cb1.w +
                     qv1.x * cb2.x + qv1.y * cb2.y + qv1.z * cb2.z + qv1.w * cb2.w;
          float n2 = cb1.x * cb1.x + cb1.y * cb1.y + cb1.z * cb1.z + cb1.w * cb1.w +
                     cb2.x * cb2.x + cb2.y * cb2.y + cb2.z * cb2.z + cb2.w * cb2.w;
          dd = row16_sum(dd);
          n2 = row16_sum(n2);
          float tsv = logmap_scale(n2);
          float4 y1 = make_float4(tsv * cb1.x, tsv * cb1.y, tsv * cb1.z, tsv * cb1.w);
          float4 y2 = make_float4(tsv * cb2.x, tsv * cb2.y, tsv * cb2.z, tsv * cb2.w);
          __half2 h01 = __float22half2_rn(make_float2(y1.x, y1.y));
          __half2 h23 = __float22half2_rn(make_float2(y1.z, y1.w));
          __half2 h45 = __float22half2_rn(make_float2(y2.x, y2.y));
          __half2 h67 = __float22half2_rn(make_float2(y2.z, y2.w));
          uint4 pk;
          pk.x = *(const unsigned*)&h01; pk.y = *(const unsigned*)&h23;
          pk.z = *(const unsigned*)&h45; pk.w = *(const unsigned*)&h67;
          *(uint4*)(yw + (size_t)k * RPI * DH + 4 * DH) = pk;
          float pw = __expf(dd * tsv * SCALE - Mb);
          lsum += pw;
          accL.x += pw * y1.x; accL.y += pw * y1.y; accL.z += pw * y1.z; accL.w += pw * y1.w;
          accH.x += pw * y2.x; accH.y += pw * y2.y; accH.z += pw * y2.z; accH.w += pw * y2.w;
        }
      }
    } else {
      // ---- fp16 y-cache pass: no logmap, half the bytes, L3-resident ----
      const __half* yr = yc_b + (size_t)(w * 8 + g) * DH + (size_t)il * 8;

      uint4 ya = *(const uint4*)(yr);
      uint4 yb = *(const uint4*)(yr + 4 * DH);

      for (int k = 0; k < KIT; ++k) {
        uint4 cya = ya, cyb = yb;
        if (k + 1 < KIT) {
          ya = *(const uint4*)(yr + (size_t)(k + 1) * RPI * DH);
          yb = *(const uint4*)(yr + (size_t)(k + 1) * RPI * DH + 4 * DH);
        }
        // group A
        {
          float2 f0 = __half22float2(*(const __half2*)&cya.x);
          float2 f1 = __half22float2(*(const __half2*)&cya.y);
          float2 f2 = __half22float2(*(const __half2*)&cya.z);
          float2 f3 = __half22float2(*(const __half2*)&cya.w);
          float dd = qv0.x * f0.x + qv0.y * f0.y + qv0.z * f1.x + qv0.w * f1.y +
                     qv1.x * f2.x + qv1.y * f2.y + qv1.z * f3.x + qv1.w * f3.y;
          dd = row16_sum(dd);
          float pw = __expf(dd * SCALE - Mb);
          lsum += pw;
          accL.x += pw * f0.x; accL.y += pw * f0.y; accL.z += pw * f1.x; accL.w += pw * f1.y;
          accH.x += pw * f2.x; accH.y += pw * f2.y; accH.z += pw * f3.x; accH.w += pw * f3.y;
        }
        // group B
        {
          float2 f0 = __half22float2(*(const __half2*)&cyb.x);
          float2 f1 = __half22float2(*(const __half2*)&cyb.y);
          float2 f2 = __half22float2(*(const __half2*)&cyb.z);
          float2 f3 = __half22float2(*(const __half2*)&cyb.w);
          float dd = qv0.x * f0.x + qv0.y * f0.y + qv0.z * f1.x + qv0.w * f1.y +
                     qv1.x * f2.x + qv1.y * f2.y + qv1.z * f3.x + qv1.w * f3.y;
          dd = row16_sum(dd);
          float pw = __expf(dd * SCALE - Mb);
          lsum += pw;
          accL.x += pw * f0.x; accL.y += pw * f0.y; accL.z += pw * f1.x; accL.w += pw * f1.y;
          accH.x += pw * f2.x; accH.y += pw * f2.y; accH.z += pw * f3.x; accH.w += pw * f3.y;
        }
      }
    }

    // fold the 4 g-groups within each wave (same d-slice, disjoint rows)
    accL.x += __shfl_xor(accL.x, 16); accL.x += __shfl_xor(accL.x, 32);
    accL.y += __shfl_xor(accL.y, 16); accL.y += __shfl_xor(accL.y, 32);
    accL.z += __shfl_xor(accL.z, 16); accL.z += __shfl_xor(accL.z, 32);
    accL.w += __shfl_xor(accL.w, 16); accL.w += __shfl_xor(accL.w, 32);
    accH.x += __shfl_xor(accH.x, 16); accH.x += __shfl_xor(accH.x, 32);
    accH.y += __shfl_xor(accH.y, 16); accH.y += __shfl_xor(accH.y, 32);
    accH.z += __shfl_xor(accH.z, 16); accH.z += __shfl_xor(accH.z, 32);
    accH.w += __shfl_xor(accH.w, 16); accH.w += __shfl_xor(accH.w, 32);
    lsum += __shfl_xor(lsum, 16); lsum += __shfl_xor(lsum, 32);
    if (g == 0) {
      *(float4*)&s_fold[w][il * 4] = accL;
      *(float4*)&s_fold[w][64 + il * 4] = accH;
      if (il == 0) s_l[w] = lsum;
    }
    __syncthreads();

    if (tid < DH) {
      float a = 0.f;
#pragma unroll
      for (int j = 0; j < WAVES; ++j) a += s_fold[j][tid];
      float L = 0.f;
#pragma unroll
      for (int j = 0; j < WAVES; ++j) L += s_l[j];
      s_x[tid] = a / L;  // weighted tangent value (= sum p*y / sum p)
    }
    __syncthreads();

    // ---- transition ----
    if (pass == 0) {
      if (tid < DH) s_y[tid] = dot128(pool_wv_w + (size_t)tid * DH, s_x);
      __syncthreads();
      float v = 0.f;
      if (tid < DH) v = s_qseed[tid] + dot128(seed_d_w + (size_t)tid * DH, s_y);
      ln_query(v);
    } else {
      if (tid < DH) s_y[tid] = dot128(kv_w + (size_t)tid * DH, s_x);
      __syncthreads();
      if (tid < HID) {
        float h = mlp_b1[tid] + dot128(mlp_w1 + (size_t)tid * DH, s_y);
        s_h[tid] = 0.5f * h * (1.0f + erff(h * 0.70710678118654752f));
      }
      __syncthreads();
      float v = 0.f;
      if (tid < DH)
        v = s_ut[tid] + mlp_b2[tid] + dot256(mlp_w2 + (size_t)tid * HID, s_h);
      if (pass == 2) {
        float n2 = bsumAll(tid < DH ? v * v : 0.f);
        if (tid < DH) {
          float nc = fmaxf(sqrtf(n2), 1e-7f);
          out[(size_t)b * DH + tid] = v * (tanhf(nc) / nc);
        }
      } else {
        ln_query(v);
      }
    }
  }
}

// ---------- launch ----------

extern "C" void kernel_launch(void* const* d_in, const int* in_sizes, int n_in,
                              void* d_out, int out_size, void* d_ws, size_t ws_size,
                              hipStream_t stream) {
  const float* demo      = (const float*)d_in[0];
  const float* rho       = (const float*)d_in[1];
  const float* seed_g_w  = (const float*)d_in[2];
  const float* seed_g_b  = (const float*)d_in[3];
  const float* seed_d_w  = (const float*)d_in[4];
  const float* pool_wq_w = (const float*)d_in[5];
  const float* pool_wk_w = (const float*)d_in[6];
  const float* pool_wv_w = (const float*)d_in[7];
  const float* q_u_w     = (const float*)d_in[8];
  const float* q_g_w     = (const float*)d_in[9];
  const float* q_g_b     = (const float*)d_in[10];
  const float* kv_w      = (const float*)d_in[11];
  const float* mlp_w1    = (const float*)d_in[12];
  const float* mlp_b1    = (const float*)d_in[13];
  const float* mlp_w2    = (const float*)d_in[14];
  const float* mlp_b2    = (const float*)d_in[15];
  const float* ln_g      = (const float*)d_in[16];
  const float* ln_b      = (const float*)d_in[17];
  float* out = (float*)d_out;
  __half* ycache = (__half*)d_ws;  // B*N*DH halves = 128 MB
  (void)ws_size; (void)in_sizes; (void)n_in; (void)out_size;

  fused_refiner<<<B, TPB, 0, stream>>>(demo, rho, seed_g_w, seed_g_b, seed_d_w,
                                       pool_wq_w, pool_wk_w, pool_wv_w, q_u_w,
                                       q_g_w, q_g_b, kv_w, mlp_w1, mlp_b1,
                                       mlp_w2, mlp_b2, ln_g, ln_b, ycache, out);
}

// Round 7
// 524.247 us; speedup vs baseline: 1.0256x; 1.0256x over previous
//
// Resubmit of round-5 kernel: bench infra failed ("container failed twice");
// no kernel-level verdict was produced. Source audited for hang hazards
// (divergent barriers, LDS overflow, workspace overrun): none found.
#include <hip/hip_runtime.h>
#include <hip/hip_fp16.h>
#include <cstddef>
#include <cstdint>

#define B 256
#define N 2048
#define DH 128
#define DG 256
#define HID 256
#define WAVES 16
#define TPB (WAVES * 64)   // 1024 threads, 16 waves, 1 block/CU
#define RPI (WAVES * 8)    // 128 rows per block-iteration
#define KIT (N / RPI)      // 16 k-iterations per pass
#define SCALE 0.08838834764831845f
#define LN_EPS 1e-5f
#define TAN_NORM_MAX 6.2f  // artanh(1-1e-5)=6.103; safe upper bound

// ---------- helpers ----------

__device__ __forceinline__ float artanh_clip(float a) {
  a = fminf(a, 1.0f - 1e-5f);
  return 0.5f * __logf((1.0f + a) / (1.0f - a));
}

__device__ __forceinline__ float logmap_scale(float n2) {
  float nc = fmaxf(sqrtf(n2), 1e-7f);
  return artanh_clip(nc) / nc;
}

// allreduce-sum across each 16-lane DPP row using ROW_ROR (pure VALU)
__device__ __forceinline__ float row16_sum(float x) {
  x += __int_as_float(__builtin_amdgcn_update_dpp(0, __float_as_int(x), 0x128, 0xF, 0xF, true)); // ror:8
  x += __int_as_float(__builtin_amdgcn_update_dpp(0, __float_as_int(x), 0x124, 0xF, 0xF, true)); // ror:4
  x += __int_as_float(__builtin_amdgcn_update_dpp(0, __float_as_int(x), 0x122, 0xF, 0xF, true)); // ror:2
  x += __int_as_float(__builtin_amdgcn_update_dpp(0, __float_as_int(x), 0x121, 0xF, 0xF, true)); // ror:1
  return x;
}

__device__ __forceinline__ float wave_allsum(float v) {
#pragma unroll
  for (int m = 1; m < 64; m <<= 1) v += __shfl_xor(v, m);
  return v;
}

__device__ __forceinline__ float dot128(const float* __restrict__ wrow,
                                        const float* __restrict__ x) {
  const float4* a = (const float4*)wrow;
  const float4* v = (const float4*)x;
  float s = 0.f;
#pragma unroll
  for (int j = 0; j < 32; ++j) {
    float4 u = a[j], b = v[j];
    s += u.x * b.x + u.y * b.y + u.z * b.z + u.w * b.w;
  }
  return s;
}

__device__ __forceinline__ float dot256(const float* __restrict__ wrow,
                                        const float* __restrict__ x) {
  const float4* a = (const float4*)wrow;
  const float4* v = (const float4*)x;
  float s = 0.f;
#pragma unroll
  for (int j = 0; j < 64; ++j) {
    float4 u = a[j], b = v[j];
    s += u.x * b.x + u.y * b.y + u.z * b.z + u.w * b.w;
  }
  return s;
}

// ---------- shared-memory block ----------

struct __align__(16) Smem {
  float rho[DG];
  float x[DH];
  float y[DH];
  float h[HID];
  float ut[DH];
  float qseed[DH];
  float qvec[DH];
  float fold[WAVES][DH];
  float l[WAVES];
  float red[WAVES];
  float Mb;
};

__device__ __forceinline__ float bsumAll(Smem& sm, float v, int w, int lane) {
  v = wave_allsum(v);
  if (lane == 0) sm.red[w] = v;
  __syncthreads();
  float r = 0.f;
#pragma unroll
  for (int j = 0; j < WAVES; ++j) r += sm.red[j];
  __syncthreads();
  return r;
}

// expmap -> logmap -> LN -> q -> qvec -> Mb (results in sm.ut / sm.qvec / sm.Mb)
__device__ __forceinline__ void ln_query(Smem& sm, float v, int tid, int w, int lane,
    const float* __restrict__ q_u_w, const float* __restrict__ q_g_w,
    const float* __restrict__ q_g_b, const float* __restrict__ kv_w,
    const float* __restrict__ ln_g, const float* __restrict__ ln_b) {
  float n2 = bsumAll(sm, tid < DH ? v * v : 0.f, w, lane);
  float u = 0.f, ut = 0.f;
  if (tid < DH) {
    float nc = fmaxf(sqrtf(n2), 1e-7f);
    u = v * (tanhf(nc) / nc);
  }
  float nu2 = bsumAll(sm, tid < DH ? u * u : 0.f, w, lane);
  if (tid < DH) {
    float nuc = fmaxf(sqrtf(nu2), 1e-7f);
    ut = u * (artanh_clip(nuc) / nuc);
  }
  float mu = bsumAll(sm, tid < DH ? ut : 0.f, w, lane) * (1.0f / DH);
  float d = ut - mu;
  float var = bsumAll(sm, tid < DH ? d * d : 0.f, w, lane) * (1.0f / DH);
  if (tid < DH) {
    float y = d * rsqrtf(var + LN_EPS) * ln_g[tid] + ln_b[tid];
    sm.ut[tid] = y;
    sm.x[tid] = y;
  }
  __syncthreads();
  if (tid < DH) {
    sm.y[tid] = q_g_b[tid] + dot128(q_u_w + (size_t)tid * DH, sm.x) +
                dot256(q_g_w + (size_t)tid * DG, sm.rho);
  }
  __syncthreads();
  float qp = 0.f;
  if (tid < DH) {
#pragma unroll 8
    for (int i = 0; i < DH; ++i) qp += kv_w[i * DH + tid] * sm.y[i];
    sm.qvec[tid] = qp;
  }
  float qn2 = bsumAll(sm, tid < DH ? qp * qp : 0.f, w, lane);
  if (tid == 0) sm.Mb = SCALE * TAN_NORM_MAX * sqrtf(qn2);
  __syncthreads();
}

// fold 4 g-groups per wave, then 16 waves; result (weighted tangent avg) in sm.x
__device__ __forceinline__ void fold_combine(Smem& sm, float4 accL, float4 accH,
                                             float lsum, int w, int g, int il, int tid) {
  accL.x += __shfl_xor(accL.x, 16); accL.x += __shfl_xor(accL.x, 32);
  accL.y += __shfl_xor(accL.y, 16); accL.y += __shfl_xor(accL.y, 32);
  accL.z += __shfl_xor(accL.z, 16); accL.z += __shfl_xor(accL.z, 32);
  accL.w += __shfl_xor(accL.w, 16); accL.w += __shfl_xor(accL.w, 32);
  accH.x += __shfl_xor(accH.x, 16); accH.x += __shfl_xor(accH.x, 32);
  accH.y += __shfl_xor(accH.y, 16); accH.y += __shfl_xor(accH.y, 32);
  accH.z += __shfl_xor(accH.z, 16); accH.z += __shfl_xor(accH.z, 32);
  accH.w += __shfl_xor(accH.w, 16); accH.w += __shfl_xor(accH.w, 32);
  lsum += __shfl_xor(lsum, 16); lsum += __shfl_xor(lsum, 32);
  if (g == 0) {
    *(float4*)&sm.fold[w][il * 4] = accL;
    *(float4*)&sm.fold[w][64 + il * 4] = accH;
    if (il == 0) sm.l[w] = lsum;
  }
  __syncthreads();
  if (tid < DH) {
    float a = 0.f, L = 0.f;
#pragma unroll
    for (int j = 0; j < WAVES; ++j) { a += sm.fold[j][tid]; L += sm.l[j]; }
    sm.x[tid] = a / L;
  }
  __syncthreads();
}

// one fp32 row: score + logmap, emit fp16 y, accumulate
__device__ __forceinline__ void proc_fp32(const float4 c1, const float4 c2,
    const float4 qv0, const float4 qv1, const float Mb,
    __half* __restrict__ yw,
    float& lsum, float4& accL, float4& accH) {
  float dd = qv0.x * c1.x + qv0.y * c1.y + qv0.z * c1.z + qv0.w * c1.w +
             qv1.x * c2.x + qv1.y * c2.y + qv1.z * c2.z + qv1.w * c2.w;
  float n2 = c1.x * c1.x + c1.y * c1.y + c1.z * c1.z + c1.w * c1.w +
             c2.x * c2.x + c2.y * c2.y + c2.z * c2.z + c2.w * c2.w;
  dd = row16_sum(dd);
  n2 = row16_sum(n2);
  float tsv = logmap_scale(n2);
  float4 y1 = make_float4(tsv * c1.x, tsv * c1.y, tsv * c1.z, tsv * c1.w);
  float4 y2 = make_float4(tsv * c2.x, tsv * c2.y, tsv * c2.z, tsv * c2.w);
  __half2 h01 = __float22half2_rn(make_float2(y1.x, y1.y));
  __half2 h23 = __float22half2_rn(make_float2(y1.z, y1.w));
  __half2 h45 = __float22half2_rn(make_float2(y2.x, y2.y));
  __half2 h67 = __float22half2_rn(make_float2(y2.z, y2.w));
  uint4 pk;
  pk.x = *(const unsigned*)&h01; pk.y = *(const unsigned*)&h23;
  pk.z = *(const unsigned*)&h45; pk.w = *(const unsigned*)&h67;
  *(uint4*)yw = pk;
  float pw = __expf(dd * tsv * SCALE - Mb);
  lsum += pw;
  accL.x += pw * y1.x; accL.y += pw * y1.y; accL.z += pw * y1.z; accL.w += pw * y1.w;
  accH.x += pw * y2.x; accH.y += pw * y2.y; accH.z += pw * y2.z; accH.w += pw * y2.w;
}

// one fp16 row: unpack, score, accumulate (no logmap chain)
__device__ __forceinline__ void proc_fp16(const uint4 pk,
    const float4 qv0, const float4 qv1, const float Mb,
    float& lsum, float4& accL, float4& accH) {
  float2 f0 = __half22float2(*(const __half2*)&pk.x);
  float2 f1 = __half22float2(*(const __half2*)&pk.y);
  float2 f2 = __half22float2(*(const __half2*)&pk.z);
  float2 f3 = __half22float2(*(const __half2*)&pk.w);
  float dd = qv0.x * f0.x + qv0.y * f0.y + qv0.z * f1.x + qv0.w * f1.y +
             qv1.x * f2.x + qv1.y * f2.y + qv1.z * f3.x + qv1.w * f3.y;
  dd = row16_sum(dd);
  float pw = __expf(dd * SCALE - Mb);
  lsum += pw;
  accL.x += pw * f0.x; accL.y += pw * f0.y; accL.z += pw * f1.x; accL.w += pw * f1.y;
  accH.x += pw * f2.x; accH.y += pw * f2.y; accH.z += pw * f3.x; accH.w += pw * f3.y;
}

// ---------- kernel A: setup + fp32 pass (emit y-cache) + pool transition ----------

__global__ __launch_bounds__(TPB) void refine_a(
    const float* __restrict__ demo, const float* __restrict__ rho,
    const float* __restrict__ seed_g_w, const float* __restrict__ seed_g_b,
    const float* __restrict__ seed_d_w, const float* __restrict__ pool_wq_w,
    const float* __restrict__ pool_wk_w, const float* __restrict__ pool_wv_w,
    const float* __restrict__ q_u_w, const float* __restrict__ q_g_w,
    const float* __restrict__ q_g_b, const float* __restrict__ kv_w,
    const float* __restrict__ ln_g, const float* __restrict__ ln_b,
    __half* __restrict__ ycache, float* __restrict__ g_ut,
    float* __restrict__ g_qvec, float* __restrict__ g_mb) {
  __shared__ Smem sm;
  const int b = blockIdx.x, tid = threadIdx.x;
  const int w = tid >> 6, lane = tid & 63;
  const int g = lane >> 4, il = lane & 15;

  if (tid < DG) sm.rho[tid] = rho[(size_t)b * DG + tid];
  __syncthreads();
  if (tid < DH) {
    float qs = seed_g_b[tid] + dot256(seed_g_w + (size_t)tid * DG, sm.rho);
    sm.qseed[tid] = qs;
    sm.x[tid] = qs;
  }
  __syncthreads();
  if (tid < DH) sm.y[tid] = dot128(pool_wq_w + (size_t)tid * DH, sm.x);
  __syncthreads();
  float qp0 = 0.f;
  if (tid < DH) {
#pragma unroll 8
    for (int i = 0; i < DH; ++i) qp0 += pool_wk_w[i * DH + tid] * sm.y[i];
    sm.qvec[tid] = qp0;
  }
  float qn2 = bsumAll(sm, tid < DH ? qp0 * qp0 : 0.f, w, lane);
  if (tid == 0) sm.Mb = SCALE * TAN_NORM_MAX * sqrtf(qn2);
  __syncthreads();

  // ---- fp32 attention pass, 2-deep double-buffer (8 KiB/wave in flight) ----
  const float* p = demo + (size_t)b * N * DH + (size_t)(w * 8 + g) * DH + il * 4;
  __half* yw = ycache + (size_t)b * N * DH + (size_t)(w * 8 + g) * DH + (size_t)il * 8;
  const float4 qv0 = *(const float4*)&sm.qvec[il * 4];
  const float4 qv1 = *(const float4*)&sm.qvec[64 + il * 4];
  const float Mb = sm.Mb;

  float lsum = 0.f;
  float4 accL = make_float4(0.f, 0.f, 0.f, 0.f);
  float4 accH = make_float4(0.f, 0.f, 0.f, 0.f);

#define LD4(s1, s2, s3, s4, kk)                                   \
  do {                                                            \
    const float* pn_ = p + (size_t)(kk) * RPI * DH;               \
    s1 = *(const float4*)(pn_);                                   \
    s2 = *(const float4*)(pn_ + 64);                              \
    s3 = *(const float4*)(pn_ + 4 * DH);                          \
    s4 = *(const float4*)(pn_ + 4 * DH + 64);                     \
  } while (0)

  float4 a1A, a2A, b1A, b2A, a1B, a2B, b1B, b2B;
  LD4(a1A, a2A, b1A, b2A, 0);
  LD4(a1B, a2B, b1B, b2B, 1);

  for (int k = 0; k < KIT; k += 2) {
    {
      float4 c1 = a1A, c2 = a2A, d1 = b1A, d2 = b2A;
      if (k + 2 < KIT) LD4(a1A, a2A, b1A, b2A, k + 2);
      proc_fp32(c1, c2, qv0, qv1, Mb, yw + (size_t)k * RPI * DH, lsum, accL, accH);
      proc_fp32(d1, d2, qv0, qv1, Mb, yw + (size_t)k * RPI * DH + 4 * DH, lsum, accL, accH);
    }
    {
      float4 c1 = a1B, c2 = a2B, d1 = b1B, d2 = b2B;
      if (k + 3 < KIT) LD4(a1B, a2B, b1B, b2B, k + 3);
      proc_fp32(c1, c2, qv0, qv1, Mb, yw + (size_t)(k + 1) * RPI * DH, lsum, accL, accH);
      proc_fp32(d1, d2, qv0, qv1, Mb, yw + (size_t)(k + 1) * RPI * DH + 4 * DH, lsum, accL, accH);
    }
  }
#undef LD4

  fold_combine(sm, accL, accH, lsum, w, g, il, tid);

  // ---- pool transition ----
  if (tid < DH) sm.y[tid] = dot128(pool_wv_w + (size_t)tid * DH, sm.x);
  __syncthreads();
  float v = 0.f;
  if (tid < DH) v = sm.qseed[tid] + dot128(seed_d_w + (size_t)tid * DH, sm.y);
  ln_query(sm, v, tid, w, lane, q_u_w, q_g_w, q_g_b, kv_w, ln_g, ln_b);
  if (tid < DH) {
    g_ut[(size_t)b * DH + tid] = sm.ut[tid];
    g_qvec[(size_t)b * DH + tid] = sm.qvec[tid];
  }
  if (tid == 0) g_mb[b] = sm.Mb;
}

// ---------- kernels B/C: fp16 pass + iter transition (FINAL=1 writes out) ----------

template <int FINAL>
__global__ __launch_bounds__(TPB) void refine_bc(
    const float* __restrict__ rho, const float* __restrict__ kv_w,
    const float* __restrict__ mlp_w1, const float* __restrict__ mlp_b1,
    const float* __restrict__ mlp_w2, const float* __restrict__ mlp_b2,
    const float* __restrict__ q_u_w, const float* __restrict__ q_g_w,
    const float* __restrict__ q_g_b, const float* __restrict__ ln_g,
    const float* __restrict__ ln_b, const __half* __restrict__ ycache,
    float* __restrict__ g_ut, float* __restrict__ g_qvec,
    float* __restrict__ g_mb, float* __restrict__ out) {
  __shared__ Smem sm;
  const int b = blockIdx.x, tid = threadIdx.x;
  const int w = tid >> 6, lane = tid & 63;
  const int g = lane >> 4, il = lane & 15;

  if (tid < DG) sm.rho[tid] = rho[(size_t)b * DG + tid];
  if (tid < DH) {
    sm.qvec[tid] = g_qvec[(size_t)b * DH + tid];
    sm.ut[tid] = g_ut[(size_t)b * DH + tid];
  }
  if (tid == 0) sm.Mb = g_mb[b];
  __syncthreads();

  // ---- fp16 attention pass, 4-deep pipeline (8 KiB/wave in flight) ----
  const __half* yr = ycache + (size_t)b * N * DH + (size_t)(w * 8 + g) * DH + (size_t)il * 8;
  const float4 qv0 = *(const float4*)&sm.qvec[il * 4];
  const float4 qv1 = *(const float4*)&sm.qvec[64 + il * 4];
  const float Mb = sm.Mb;

  float lsum = 0.f;
  float4 accL = make_float4(0.f, 0.f, 0.f, 0.f);
  float4 accH = make_float4(0.f, 0.f, 0.f, 0.f);

#define LDY(sa, sb, kk)                                           \
  do {                                                            \
    const __half* pn_ = yr + (size_t)(kk) * RPI * DH;             \
    sa = *(const uint4*)(pn_);                                    \
    sb = *(const uint4*)(pn_ + 4 * DH);                           \
  } while (0)

  uint4 y0a, y0b, y1a, y1b, y2a, y2b, y3a, y3b;
  LDY(y0a, y0b, 0);
  LDY(y1a, y1b, 1);
  LDY(y2a, y2b, 2);
  LDY(y3a, y3b, 3);

  for (int k = 0; k < KIT; k += 4) {
    {
      uint4 pa = y0a, pb = y0b;
      if (k + 4 < KIT) LDY(y0a, y0b, k + 4);
      proc_fp16(pa, qv0, qv1, Mb, lsum, accL, accH);
      proc_fp16(pb, qv0, qv1, Mb, lsum, accL, accH);
    }
    {
      uint4 pa = y1a, pb = y1b;
      if (k + 5 < KIT) LDY(y1a, y1b, k + 5);
      proc_fp16(pa, qv0, qv1, Mb, lsum, accL, accH);
      proc_fp16(pb, qv0, qv1, Mb, lsum, accL, accH);
    }
    {
      uint4 pa = y2a, pb = y2b;
      if (k + 6 < KIT) LDY(y2a, y2b, k + 6);
      proc_fp16(pa, qv0, qv1, Mb, lsum, accL, accH);
      proc_fp16(pb, qv0, qv1, Mb, lsum, accL, accH);
    }
    {
      uint4 pa = y3a, pb = y3b;
      if (k + 7 < KIT) LDY(y3a, y3b, k + 7);
      proc_fp16(pa, qv0, qv1, Mb, lsum, accL, accH);
      proc_fp16(pb, qv0, qv1, Mb, lsum, accL, accH);
    }
  }
#undef LDY

  fold_combine(sm, accL, accH, lsum, w, g, il, tid);

  // ---- iteration transition ----
  if (tid < DH) sm.y[tid] = dot128(kv_w + (size_t)tid * DH, sm.x);
  __syncthreads();
  if (tid < HID) {
    float hh = mlp_b1[tid] + dot128(mlp_w1 + (size_t)tid * DH, sm.y);
    sm.h[tid] = 0.5f * hh * (1.0f + erff(hh * 0.70710678118654752f));
  }
  __syncthreads();
  float v = 0.f;
  if (tid < DH)
    v = sm.ut[tid] + mlp_b2[tid] + dot256(mlp_w2 + (size_t)tid * HID, sm.h);
  if (FINAL) {
    float n2 = bsumAll(sm, tid < DH ? v * v : 0.f, w, lane);
    if (tid < DH) {
      float nc = fmaxf(sqrtf(n2), 1e-7f);
      out[(size_t)b * DH + tid] = v * (tanhf(nc) / nc);
    }
  } else {
    ln_query(sm, v, tid, w, lane, q_u_w, q_g_w, q_g_b, kv_w, ln_g, ln_b);
    if (tid < DH) {
      g_ut[(size_t)b * DH + tid] = sm.ut[tid];
      g_qvec[(size_t)b * DH + tid] = sm.qvec[tid];
    }
    if (tid == 0) g_mb[b] = sm.Mb;
  }
}

// ---------- launch ----------

extern "C" void kernel_launch(void* const* d_in, const int* in_sizes, int n_in,
                              void* d_out, int out_size, void* d_ws, size_t ws_size,
                              hipStream_t stream) {
  const float* demo      = (const float*)d_in[0];
  const float* rho       = (const float*)d_in[1];
  const float* seed_g_w  = (const float*)d_in[2];
  const float* seed_g_b  = (const float*)d_in[3];
  const float* seed_d_w  = (const float*)d_in[4];
  const float* pool_wq_w = (const float*)d_in[5];
  const float* pool_wk_w = (const float*)d_in[6];
  const float* pool_wv_w = (const float*)d_in[7];
  const float* q_u_w     = (const float*)d_in[8];
  const float* q_g_w     = (const float*)d_in[9];
  const float* q_g_b     = (const float*)d_in[10];
  const float* kv_w      = (const float*)d_in[11];
  const float* mlp_w1    = (const float*)d_in[12];
  const float* mlp_b1    = (const float*)d_in[13];
  const float* mlp_w2    = (const float*)d_in[14];
  const float* mlp_b2    = (const float*)d_in[15];
  const float* ln_g      = (const float*)d_in[16];
  const float* ln_b      = (const float*)d_in[17];
  float* out = (float*)d_out;

  __half* ycache = (__half*)d_ws;                              // B*N*DH halves = 128 MB
  float* fw = (float*)(ycache + (size_t)B * N * DH);
  float* g_ut   = fw;                                          // B*DH
  float* g_qvec = fw + (size_t)B * DH;                         // B*DH
  float* g_mb   = fw + (size_t)2 * B * DH;                     // B
  (void)ws_size; (void)in_sizes; (void)n_in; (void)out_size;

  refine_a<<<B, TPB, 0, stream>>>(demo, rho, seed_g_w, seed_g_b, seed_d_w,
                                  pool_wq_w, pool_wk_w, pool_wv_w, q_u_w, q_g_w,
                                  q_g_b, kv_w, ln_g, ln_b, ycache, g_ut, g_qvec,
                                  g_mb);
  refine_bc<0><<<B, TPB, 0, stream>>>(rho, kv_w, mlp_w1, mlp_b1, mlp_w2, mlp_b2,
                                      q_u_w, q_g_w, q_g_b, ln_g, ln_b, ycache,
                                      g_ut, g_qvec, g_mb, out);
  refine_bc<1><<<B, TPB, 0, stream>>>(rho, kv_w, mlp_w1, mlp_b1, mlp_w2, mlp_b2,
                                      q_u_w, q_g_w, q_g_b, ln_g, ln_b, ycache,
                                      g_ut, g_qvec, g_mb, out);
}

// Round 8
// 519.171 us; speedup vs baseline: 1.0357x; 1.0098x over previous
//
#include <hip/hip_runtime.h>
#include <hip/hip_fp16.h>
#include <cstddef>
#include <cstdint>

#define B 256
#define N 2048
#define DH 128
#define DG 256
#define HID 256
#define WAVES 16
#define TPB (WAVES * 64)   // 1024 threads, 16 waves, 1 block/CU
#define TROWS 64           // rows per tile (4 per wave)
#define KITER (N / TROWS)  // 32 tiles per pass
#define SCALE 0.08838834764831845f
#define LN_EPS 1e-5f
#define TAN_NORM_MAX 6.2f  // artanh(1-1e-5)=6.103; safe upper bound

// ---------- helpers ----------

__device__ __forceinline__ float artanh_clip(float a) {
  a = fminf(a, 1.0f - 1e-5f);
  return 0.5f * __logf((1.0f + a) / (1.0f - a));
}

__device__ __forceinline__ float logmap_scale(float n2) {
  float nc = fmaxf(sqrtf(n2), 1e-7f);
  return artanh_clip(nc) / nc;
}

// allreduce-sum across each 16-lane DPP row using ROW_ROR (pure VALU)
__device__ __forceinline__ float row16_sum(float x) {
  x += __int_as_float(__builtin_amdgcn_update_dpp(0, __float_as_int(x), 0x128, 0xF, 0xF, true)); // ror:8
  x += __int_as_float(__builtin_amdgcn_update_dpp(0, __float_as_int(x), 0x124, 0xF, 0xF, true)); // ror:4
  x += __int_as_float(__builtin_amdgcn_update_dpp(0, __float_as_int(x), 0x122, 0xF, 0xF, true)); // ror:2
  x += __int_as_float(__builtin_amdgcn_update_dpp(0, __float_as_int(x), 0x121, 0xF, 0xF, true)); // ror:1
  return x;
}

__device__ __forceinline__ float wave_allsum(float v) {
#pragma unroll
  for (int m = 1; m < 64; m <<= 1) v += __shfl_xor(v, m);
  return v;
}

__device__ __forceinline__ float dot128(const float* __restrict__ wrow,
                                        const float* __restrict__ x) {
  const float4* a = (const float4*)wrow;
  const float4* v = (const float4*)x;
  float s = 0.f;
#pragma unroll
  for (int j = 0; j < 32; ++j) {
    float4 u = a[j], b = v[j];
    s += u.x * b.x + u.y * b.y + u.z * b.z + u.w * b.w;
  }
  return s;
}

__device__ __forceinline__ float dot256(const float* __restrict__ wrow,
                                        const float* __restrict__ x) {
  const float4* a = (const float4*)wrow;
  const float4* v = (const float4*)x;
  float s = 0.f;
#pragma unroll
  for (int j = 0; j < 64; ++j) {
    float4 u = a[j], b = v[j];
    s += u.x * b.x + u.y * b.y + u.z * b.z + u.w * b.w;
  }
  return s;
}

// ---------- global->LDS DMA (wave-contiguous 1 KB per instruction) ----------

typedef __attribute__((address_space(3))) void lds_vp;
typedef __attribute__((address_space(1))) const void gm_vp;
__device__ __forceinline__ void dma16(const void* g, void* l) {
  // per-lane global addr; LDS dest = wave-uniform base + lane*16
  __builtin_amdgcn_global_load_lds((gm_vp*)g, (lds_vp*)l, 16, 0, 0);
}

// ---------- shared-memory block ----------

struct __align__(16) Smem {
  float rho[DG];
  float x[DH];
  float y[DH];
  float h[HID];
  float ut[DH];
  float qseed[DH];
  float qvec[DH];
  float fold[WAVES][DH];
  float l[WAVES];
  float red[WAVES];
  float Mb;
};

__device__ __forceinline__ float bsumAll(Smem& sm, float v, int w, int lane) {
  v = wave_allsum(v);
  if (lane == 0) sm.red[w] = v;
  __syncthreads();
  float r = 0.f;
#pragma unroll
  for (int j = 0; j < WAVES; ++j) r += sm.red[j];
  __syncthreads();
  return r;
}

// expmap -> logmap -> LN -> q -> qvec -> Mb (results in sm.ut / sm.qvec / sm.Mb)
__device__ __forceinline__ void ln_query(Smem& sm, float v, int tid, int w, int lane,
    const float* __restrict__ q_u_w, const float* __restrict__ q_g_w,
    const float* __restrict__ q_g_b, const float* __restrict__ kv_w,
    const float* __restrict__ ln_g, const float* __restrict__ ln_b) {
  float n2 = bsumAll(sm, tid < DH ? v * v : 0.f, w, lane);
  float u = 0.f, ut = 0.f;
  if (tid < DH) {
    float nc = fmaxf(sqrtf(n2), 1e-7f);
    u = v * (tanhf(nc) / nc);
  }
  float nu2 = bsumAll(sm, tid < DH ? u * u : 0.f, w, lane);
  if (tid < DH) {
    float nuc = fmaxf(sqrtf(nu2), 1e-7f);
    ut = u * (artanh_clip(nuc) / nuc);
  }
  float mu = bsumAll(sm, tid < DH ? ut : 0.f, w, lane) * (1.0f / DH);
  float d = ut - mu;
  float var = bsumAll(sm, tid < DH ? d * d : 0.f, w, lane) * (1.0f / DH);
  if (tid < DH) {
    float y = d * rsqrtf(var + LN_EPS) * ln_g[tid] + ln_b[tid];
    sm.ut[tid] = y;
    sm.x[tid] = y;
  }
  __syncthreads();
  if (tid < DH) {
    sm.y[tid] = q_g_b[tid] + dot128(q_u_w + (size_t)tid * DH, sm.x) +
                dot256(q_g_w + (size_t)tid * DG, sm.rho);
  }
  __syncthreads();
  float qp = 0.f;
  if (tid < DH) {
#pragma unroll 8
    for (int i = 0; i < DH; ++i) qp += kv_w[i * DH + tid] * sm.y[i];
    sm.qvec[tid] = qp;
  }
  float qn2 = bsumAll(sm, tid < DH ? qp * qp : 0.f, w, lane);
  if (tid == 0) sm.Mb = SCALE * TAN_NORM_MAX * sqrtf(qn2);
  __syncthreads();
}

// fold 4 g-groups per wave, then 16 waves; result (weighted tangent avg) in sm.x
__device__ __forceinline__ void fold_combine(Smem& sm, float4 accL, float4 accH,
                                             float lsum, int w, int g, int il, int tid) {
  accL.x += __shfl_xor(accL.x, 16); accL.x += __shfl_xor(accL.x, 32);
  accL.y += __shfl_xor(accL.y, 16); accL.y += __shfl_xor(accL.y, 32);
  accL.z += __shfl_xor(accL.z, 16); accL.z += __shfl_xor(accL.z, 32);
  accL.w += __shfl_xor(accL.w, 16); accL.w += __shfl_xor(accL.w, 32);
  accH.x += __shfl_xor(accH.x, 16); accH.x += __shfl_xor(accH.x, 32);
  accH.y += __shfl_xor(accH.y, 16); accH.y += __shfl_xor(accH.y, 32);
  accH.z += __shfl_xor(accH.z, 16); accH.z += __shfl_xor(accH.z, 32);
  accH.w += __shfl_xor(accH.w, 16); accH.w += __shfl_xor(accH.w, 32);
  lsum += __shfl_xor(lsum, 16); lsum += __shfl_xor(lsum, 32);
  if (g == 0) {
    *(float4*)&sm.fold[w][il * 4] = accL;
    *(float4*)&sm.fold[w][64 + il * 4] = accH;
    if (il == 0) sm.l[w] = lsum;
  }
  __syncthreads();
  if (tid < DH) {
    float a = 0.f, L = 0.f;
#pragma unroll
    for (int j = 0; j < WAVES; ++j) { a += sm.fold[j][tid]; L += sm.l[j]; }
    sm.x[tid] = a / L;
  }
  __syncthreads();
}

// one fp32 row: score + logmap, emit fp16 y, accumulate
__device__ __forceinline__ void proc_fp32(const float4 c1, const float4 c2,
    const float4 qv0, const float4 qv1, const float Mb,
    __half* __restrict__ yw,
    float& lsum, float4& accL, float4& accH) {
  float dd = qv0.x * c1.x + qv0.y * c1.y + qv0.z * c1.z + qv0.w * c1.w +
             qv1.x * c2.x + qv1.y * c2.y + qv1.z * c2.z + qv1.w * c2.w;
  float n2 = c1.x * c1.x + c1.y * c1.y + c1.z * c1.z + c1.w * c1.w +
             c2.x * c2.x + c2.y * c2.y + c2.z * c2.z + c2.w * c2.w;
  dd = row16_sum(dd);
  n2 = row16_sum(n2);
  float tsv = logmap_scale(n2);
  float4 y1 = make_float4(tsv * c1.x, tsv * c1.y, tsv * c1.z, tsv * c1.w);
  float4 y2 = make_float4(tsv * c2.x, tsv * c2.y, tsv * c2.z, tsv * c2.w);
  __half2 h01 = __float22half2_rn(make_float2(y1.x, y1.y));
  __half2 h23 = __float22half2_rn(make_float2(y1.z, y1.w));
  __half2 h45 = __float22half2_rn(make_float2(y2.x, y2.y));
  __half2 h67 = __float22half2_rn(make_float2(y2.z, y2.w));
  uint4 pk;
  pk.x = *(const unsigned*)&h01; pk.y = *(const unsigned*)&h23;
  pk.z = *(const unsigned*)&h45; pk.w = *(const unsigned*)&h67;
  *(uint4*)yw = pk;
  float pw = __expf(dd * tsv * SCALE - Mb);
  lsum += pw;
  accL.x += pw * y1.x; accL.y += pw * y1.y; accL.z += pw * y1.z; accL.w += pw * y1.w;
  accH.x += pw * y2.x; accH.y += pw * y2.y; accH.z += pw * y2.z; accH.w += pw * y2.w;
}

// one fp16 row: unpack, score, accumulate (no logmap chain)
__device__ __forceinline__ void proc_fp16(const uint4 pk,
    const float4 qv0, const float4 qv1, const float Mb,
    float& lsum, float4& accL, float4& accH) {
  float2 f0 = __half22float2(*(const __half2*)&pk.x);
  float2 f1 = __half22float2(*(const __half2*)&pk.y);
  float2 f2 = __half22float2(*(const __half2*)&pk.z);
  float2 f3 = __half22float2(*(const __half2*)&pk.w);
  float dd = qv0.x * f0.x + qv0.y * f0.y + qv0.z * f1.x + qv0.w * f1.y +
             qv1.x * f2.x + qv1.y * f2.y + qv1.z * f3.x + qv1.w * f3.y;
  dd = row16_sum(dd);
  float pw = __expf(dd * SCALE - Mb);
  lsum += pw;
  accL.x += pw * f0.x; accL.y += pw * f0.y; accL.z += pw * f1.x; accL.w += pw * f1.y;
  accH.x += pw * f2.x; accH.y += pw * f2.y; accH.z += pw * f3.x; accH.w += pw * f3.y;
}

// ---------- kernel A: setup + fp32 pass (DMA-staged, emit y-cache) + pool transition ----------

__global__ __launch_bounds__(TPB) void refine_a(
    const float* __restrict__ demo, const float* __restrict__ rho,
    const float* __restrict__ seed_g_w, const float* __restrict__ seed_g_b,
    const float* __restrict__ seed_d_w, const float* __restrict__ pool_wq_w,
    const float* __restrict__ pool_wk_w, const float* __restrict__ pool_wv_w,
    const float* __restrict__ q_u_w, const float* __restrict__ q_g_w,
    const float* __restrict__ q_g_b, const float* __restrict__ kv_w,
    const float* __restrict__ ln_g, const float* __restrict__ ln_b,
    __half* __restrict__ ycache, float* __restrict__ g_ut,
    float* __restrict__ g_qvec, float* __restrict__ g_mb) {
  __shared__ Smem sm;
  __shared__ __align__(16) char stg[WAVES * 2 * 2048];  // 64 KB: per-wave 2x2KB dbuf
  const int b = blockIdx.x, tid = threadIdx.x;
  const int w = tid >> 6, lane = tid & 63;
  const int g = lane >> 4, il = lane & 15;

  if (tid < DG) sm.rho[tid] = rho[(size_t)b * DG + tid];
  __syncthreads();
  if (tid < DH) {
    float qs = seed_g_b[tid] + dot256(seed_g_w + (size_t)tid * DG, sm.rho);
    sm.qseed[tid] = qs;
    sm.x[tid] = qs;
  }
  __syncthreads();
  if (tid < DH) sm.y[tid] = dot128(pool_wq_w + (size_t)tid * DH, sm.x);
  __syncthreads();
  float qp0 = 0.f;
  if (tid < DH) {
#pragma unroll 8
    for (int i = 0; i < DH; ++i) qp0 += pool_wk_w[i * DH + tid] * sm.y[i];
    sm.qvec[tid] = qp0;
  }
  float qn2 = bsumAll(sm, tid < DH ? qp0 * qp0 : 0.f, w, lane);
  if (tid == 0) sm.Mb = SCALE * TAN_NORM_MAX * sqrtf(qn2);
  __syncthreads();  // drains all vmem: clean vmcnt slate for counted waits below

  // ---- fp32 attention pass: per-wave-private LDS double buffer, NO barriers.
  // Stage tile t+1 (2x dma16 = wave-contiguous 1KB each), counted vmcnt wait for
  // tile t (in-order retirement, m135), process 4 rows (g-groups) from LDS.
  const float* demo_b = demo + (size_t)b * N * DH;
  const float4 qv0 = *(const float4*)&sm.qvec[il * 4];
  const float4 qv1 = *(const float4*)&sm.qvec[64 + il * 4];
  const float Mb = sm.Mb;
  __half* yw = ycache + (size_t)b * N * DH + (size_t)(w * 4 + g) * DH + (size_t)il * 8;

  char* mybuf = stg + (size_t)w * 4096;
  const char* gsrc0 = (const char*)demo_b + (size_t)(w * 4) * 512 + (size_t)lane * 16;

  float lsum = 0.f;
  float4 accL = make_float4(0.f, 0.f, 0.f, 0.f);
  float4 accH = make_float4(0.f, 0.f, 0.f, 0.f);

  auto stage32 = [&](int t, int sel) {
    const char* s = gsrc0 + (size_t)t * (TROWS * 512);
    char* d = mybuf + sel * 2048;
    dma16(s, d);
    dma16(s + 1024, d + 1024);
  };
  auto proc_tile32 = [&](int sel, int t) {
    const float* lb = (const float*)(mybuf + sel * 2048);
    float4 c1 = *(const float4*)(lb + g * 128 + il * 4);
    float4 c2 = *(const float4*)(lb + g * 128 + 64 + il * 4);
    proc_fp32(c1, c2, qv0, qv1, Mb, yw + (size_t)t * TROWS * DH, lsum, accL, accH);
  };

  stage32(0, 0);
  stage32(1, 1);
  // peel k=0: in-flight {stage0:2, stage1:2} -> wait <=2 ensures stage0 landed
  asm volatile("s_waitcnt vmcnt(2)" ::: "memory");
  proc_tile32(0, 0);
  for (int k = 1; k < KITER; ++k) {
    stage32(k + 1 < KITER ? k + 1 : 0, (k + 1) & 1);  // dummy re-stage on last iter keeps counts uniform
    // in-flight {stage(k):2, store(k-1):1, stage(k+1):2} -> <=3 ensures stage(k) landed
    asm volatile("s_waitcnt vmcnt(3)" ::: "memory");
    proc_tile32(k & 1, k);
  }

  fold_combine(sm, accL, accH, lsum, w, g, il, tid);

  // ---- pool transition ----
  if (tid < DH) sm.y[tid] = dot128(pool_wv_w + (size_t)tid * DH, sm.x);
  __syncthreads();
  float v = 0.f;
  if (tid < DH) v = sm.qseed[tid] + dot128(seed_d_w + (size_t)tid * DH, sm.y);
  ln_query(sm, v, tid, w, lane, q_u_w, q_g_w, q_g_b, kv_w, ln_g, ln_b);
  if (tid < DH) {
    g_ut[(size_t)b * DH + tid] = sm.ut[tid];
    g_qvec[(size_t)b * DH + tid] = sm.qvec[tid];
  }
  if (tid == 0) g_mb[b] = sm.Mb;
}

// ---------- kernels B/C: DMA-staged fp16 pass + iter transition (FINAL=1 writes out) ----------

template <int FINAL>
__global__ __launch_bounds__(TPB) void refine_bc(
    const float* __restrict__ rho, const float* __restrict__ kv_w,
    const float* __restrict__ mlp_w1, const float* __restrict__ mlp_b1,
    const float* __restrict__ mlp_w2, const float* __restrict__ mlp_b2,
    const float* __restrict__ q_u_w, const float* __restrict__ q_g_w,
    const float* __restrict__ q_g_b, const float* __restrict__ ln_g,
    const float* __restrict__ ln_b, const __half* __restrict__ ycache,
    float* __restrict__ g_ut, float* __restrict__ g_qvec,
    float* __restrict__ g_mb, float* __restrict__ out) {
  __shared__ Smem sm;
  __shared__ __align__(16) char stg[WAVES * 2 * 1024];  // 32 KB: per-wave 2x1KB dbuf
  const int b = blockIdx.x, tid = threadIdx.x;
  const int w = tid >> 6, lane = tid & 63;
  const int g = lane >> 4, il = lane & 15;

  if (tid < DG) sm.rho[tid] = rho[(size_t)b * DG + tid];
  if (tid < DH) {
    sm.qvec[tid] = g_qvec[(size_t)b * DH + tid];
    sm.ut[tid] = g_ut[(size_t)b * DH + tid];
  }
  if (tid == 0) sm.Mb = g_mb[b];
  __syncthreads();  // drains vmem: clean vmcnt slate

  const __half* yc_b = ycache + (size_t)b * N * DH;
  const float4 qv0 = *(const float4*)&sm.qvec[il * 4];
  const float4 qv1 = *(const float4*)&sm.qvec[64 + il * 4];
  const float Mb = sm.Mb;

  char* mybuf = stg + (size_t)w * 2048;
  const char* gsrc0 = (const char*)yc_b + (size_t)(w * 4) * 256 + (size_t)lane * 16;

  float lsum = 0.f;
  float4 accL = make_float4(0.f, 0.f, 0.f, 0.f);
  float4 accH = make_float4(0.f, 0.f, 0.f, 0.f);

  auto stage16 = [&](int t, int sel) {
    dma16(gsrc0 + (size_t)t * (TROWS * 256), mybuf + sel * 1024);
  };
  auto proc_tile16 = [&](int sel) {
    const char* lb = mybuf + sel * 1024;
    uint4 pk = *(const uint4*)(lb + g * 256 + il * 16);
    proc_fp16(pk, qv0, qv1, Mb, lsum, accL, accH);
  };

  stage16(0, 0);
  for (int k = 0; k < KITER; ++k) {
    stage16(k + 1 < KITER ? k + 1 : 0, (k + 1) & 1);
    // in-flight {stage(k):1, stage(k+1):1} -> <=1 ensures stage(k) landed
    asm volatile("s_waitcnt vmcnt(1)" ::: "memory");
    proc_tile16(k & 1);
  }

  fold_combine(sm, accL, accH, lsum, w, g, il, tid);

  // ---- iteration transition ----
  if (tid < DH) sm.y[tid] = dot128(kv_w + (size_t)tid * DH, sm.x);
  __syncthreads();
  if (tid < HID) {
    float hh = mlp_b1[tid] + dot128(mlp_w1 + (size_t)tid * DH, sm.y);
    sm.h[tid] = 0.5f * hh * (1.0f + erff(hh * 0.70710678118654752f));
  }
  __syncthreads();
  float v = 0.f;
  if (tid < DH)
    v = sm.ut[tid] + mlp_b2[tid] + dot256(mlp_w2 + (size_t)tid * HID, sm.h);
  if (FINAL) {
    float n2 = bsumAll(sm, tid < DH ? v * v : 0.f, w, lane);
    if (tid < DH) {
      float nc = fmaxf(sqrtf(n2), 1e-7f);
      out[(size_t)b * DH + tid] = v * (tanhf(nc) / nc);
    }
  } else {
    ln_query(sm, v, tid, w, lane, q_u_w, q_g_w, q_g_b, kv_w, ln_g, ln_b);
    if (tid < DH) {
      g_ut[(size_t)b * DH + tid] = sm.ut[tid];
      g_qvec[(size_t)b * DH + tid] = sm.qvec[tid];
    }
    if (tid == 0) g_mb[b] = sm.Mb;
  }
}

// ---------- launch ----------

extern "C" void kernel_launch(void* const* d_in, const int* in_sizes, int n_in,
                              void* d_out, int out_size, void* d_ws, size_t ws_size,
                              hipStream_t stream) {
  const float* demo      = (const float*)d_in[0];
  const float* rho       = (const float*)d_in[1];
  const float* seed_g_w  = (const float*)d_in[2];
  const float* seed_g_b  = (const float*)d_in[3];
  const float* seed_d_w  = (const float*)d_in[4];
  const float* pool_wq_w = (const float*)d_in[5];
  const float* pool_wk_w = (const float*)d_in[6];
  const float* pool_wv_w = (const float*)d_in[7];
  const float* q_u_w     = (const float*)d_in[8];
  const float* q_g_w     = (const float*)d_in[9];
  const float* q_g_b     = (const float*)d_in[10];
  const float* kv_w      = (const float*)d_in[11];
  const float* mlp_w1    = (const float*)d_in[12];
  const float* mlp_b1    = (const float*)d_in[13];
  const float* mlp_w2    = (const float*)d_in[14];
  const float* mlp_b2    = (const float*)d_in[15];
  const float* ln_g      = (const float*)d_in[16];
  const float* ln_b      = (const float*)d_in[17];
  float* out = (float*)d_out;

  __half* ycache = (__half*)d_ws;                              // B*N*DH halves = 128 MB
  float* fw = (float*)(ycache + (size_t)B * N * DH);
  float* g_ut   = fw;                                          // B*DH
  float* g_qvec = fw + (size_t)B * DH;                         // B*DH
  float* g_mb   = fw + (size_t)2 * B * DH;                     // B
  (void)ws_size; (void)in_sizes; (void)n_in; (void)out_size;

  refine_a<<<B, TPB, 0, stream>>>(demo, rho, seed_g_w, seed_g_b, seed_d_w,
                                  pool_wq_w, pool_wk_w, pool_wv_w, q_u_w, q_g_w,
                                  q_g_b, kv_w, ln_g, ln_b, ycache, g_ut, g_qvec,
                                  g_mb);
  refine_bc<0><<<B, TPB, 0, stream>>>(rho, kv_w, mlp_w1, mlp_b1, mlp_w2, mlp_b2,
                                      q_u_w, q_g_w, q_g_b, ln_g, ln_b, ycache,
                                      g_ut, g_qvec, g_mb, out);
  refine_bc<1><<<B, TPB, 0, stream>>>(rho, kv_w, mlp_w1, mlp_b1, mlp_w2, mlp_b2,
                                      q_u_w, q_g_w, q_g_b, ln_g, ln_b, ycache,
                                      g_ut, g_qvec, g_mb, out);
}